// Round 1
// baseline (108814.563 us; speedup 1.0000x reference)
//
#include <hip/hip_runtime.h>
#include <stdint.h>
#include <stddef.h>

// LSTMQNetwork: B=64, T=4096, D=128, H=512, A=18
//
// Persistent-RNN design:
//  - grid 256 blocks x 256 threads (4 waves) -> 1 block/CU, all co-resident.
//  - 8 groups (bid&7 ~ XCD), each owns 8 batch rows for the whole sequence.
//  - 32 CUs per group; CU k owns h-cols [k*16, k*16+16) i.e. 64 gate cols.
//  - Wh/Wi slices stationary in VGPRs as bf16 MFMA B-frags (no LDS at all).
//  - per-step h exchange via global double-buffered h_glob (bf16) + per-CU
//    monotonic flag counters (each of 4 waves adds 1 per step). Consumers
//    spin on relaxed agent-scope atomic loads then acquire-fence.
//  - gates gathered across lanes with shfl_xor(4,8,12) (gate id = bits 2:3
//    of the 16-wide B-tile column index); c state lives in registers.
//  - qs[t-1] computed by CUs k=0,1 from the full-h A-frags loaded at step t,
//    AFTER publishing h (off the group's critical path). Epilogue step t==T
//    computes qs[T-1].

#define B_   64
#define T_   4096
#define D_   128
#define H_   512
#define G4_  2048
#define A_   18
#define NGRP 8
#define NCU  32
#define GB   8

typedef float f32x4  __attribute__((ext_vector_type(4)));
typedef short bf16x8 __attribute__((ext_vector_type(8)));

#define MFMA __builtin_amdgcn_mfma_f32_16x16x32_bf16

// workspace layout
#define FLAGS_WORDS (NGRP * NCU)
#define HG_OFF      1024                    // bytes; flags occupy [0,1024)
#define HG_ELEMS    (2 * NGRP * 16 * H_)    // 131072 bf16 elements (256 KiB)

__device__ __forceinline__ short f2bf(float x) {
    union { float f; uint32_t u; } v; v.f = x;
    uint32_t r = (v.u + 0x7fffu + ((v.u >> 16) & 1u)) >> 16;  // RNE
    return (short)(uint16_t)r;
}
__device__ __forceinline__ float sigm(float x) {
    return __builtin_amdgcn_rcpf(1.0f + __builtin_amdgcn_exp2f(-1.4426950408889634f * x));
}
__device__ __forceinline__ float tanh_(float x) {
    return 2.0f * __builtin_amdgcn_rcpf(1.0f + __builtin_amdgcn_exp2f(-2.8853900817779268f * x)) - 1.0f;
}

__global__ void lstm_init(const float* __restrict__ init_h,
                          unsigned* __restrict__ flags,
                          short* __restrict__ hg) {
    int idx = blockIdx.x * blockDim.x + threadIdx.x;
    int nt  = gridDim.x * blockDim.x;
    if (idx < FLAGS_WORDS) flags[idx] = 0u;
    for (int e = idx; e < HG_ELEMS; e += nt) {
        int col = e & (H_ - 1);
        int row = (e >> 9) & 15;
        int g   = (e >> 13) & 7;
        int buf = e >> 16;
        float v = 0.0f;
        if (buf == 0 && row < GB) v = init_h[(g * GB + row) * H_ + col];
        hg[e] = f2bf(v);
    }
}

__global__ void __launch_bounds__(256, 1) lstm_main(
    const float* __restrict__ obses, const float* __restrict__ init_c,
    const float* __restrict__ Wi,    const float* __restrict__ Wh,
    const float* __restrict__ bvec,  const float* __restrict__ Wv,
    const float* __restrict__ bv,    float* __restrict__ out,
    unsigned* flags, short* hg)
{
    const int bid = blockIdx.x;
    const int gx  = bid & 7;            // group (~XCD)
    const int k   = bid >> 3;           // CU index in group, 0..31
    const int w   = threadIdx.x >> 6;   // wave 0..3
    const int l   = threadIdx.x & 63;   // lane
    const int n   = l & 15;             // B-tile column / A row (batch)
    const int kg  = l >> 4;             // K subgroup 0..3

    const int hcol = k * 16 + w * 4 + (n & 3);   // owned h column
    const int gte  = n >> 2;                     // gate id 0..3 (i,f,g,o)
    const int gcol = gte * 512 + hcol;           // column in (4H)

    // ---- stationary weight fragments (bf16 B-frags) ----
    bf16x8 whF[16];
#pragma unroll
    for (int ch = 0; ch < 16; ++ch) {
        bf16x8 v;
#pragma unroll
        for (int j = 0; j < 8; ++j) {
            int kr = ch * 32 + kg * 8 + j;
            v[j] = f2bf(Wh[(size_t)kr * G4_ + gcol]);
        }
        whF[ch] = v;
    }
    bf16x8 wiF[4];
#pragma unroll
    for (int ch = 0; ch < 4; ++ch) {
        bf16x8 v;
#pragma unroll
        for (int j = 0; j < 8; ++j) {
            int kr = ch * 32 + kg * 8 + j;
            v[j] = f2bf(Wi[(size_t)kr * G4_ + gcol]);
        }
        wiF[ch] = v;
    }
    const float breg = bvec[gcol];

    // qs weights: only CUs k=0,1 use them (cols k*16+n)
    const int qcol = k * 16 + n;
    const bool qcu = (k < 2);
    bf16x8 wvF[16];
#pragma unroll
    for (int ch = 0; ch < 16; ++ch) {
        bf16x8 v;
#pragma unroll
        for (int j = 0; j < 8; ++j) {
            int kr = ch * 32 + kg * 8 + j;
            float x = (qcu && qcol < A_) ? Wv[(size_t)kr * A_ + qcol] : 0.0f;
            v[j] = f2bf(x);
        }
        wvF[ch] = v;
    }
    const float bvv = (qcu && qcol < A_) ? bv[qcol] : 0.0f;

    // c state: rows kg*4+r (valid kg<2), col hcol (valid n<4)
    const bool owner = (kg < 2) && (n < 4);
    float cst[4];
#pragma unroll
    for (int r = 0; r < 4; ++r)
        cst[r] = owner ? init_c[(size_t)(gx * GB + kg * 4 + r) * H_ + hcol] : 0.0f;
    float hlast[4] = {0.f, 0.f, 0.f, 0.f};

    unsigned* gflags = flags + gx * NCU;

    for (int t = 0; t <= T_; ++t) {
        const bool last = (t == T_);
        if (last && !qcu) break;

        f32x4 acc0, acc1;
        if (!last) {
            // obs A-frags for step t (rows = batch n, zeros for n>=8)
            bf16x8 obsF[4];
#pragma unroll
            for (int ch = 0; ch < 4; ++ch) {
                bf16x8 v;
                if (n < GB) {
                    const float* src = obses + ((size_t)(gx * GB + n) * T_ + t) * D_ + ch * 32 + kg * 8;
                    f32x4 a = *(const f32x4*)src;
                    f32x4 b2 = *(const f32x4*)(src + 4);
#pragma unroll
                    for (int j = 0; j < 4; ++j) { v[j] = f2bf(a[j]); v[4 + j] = f2bf(b2[j]); }
                } else {
#pragma unroll
                    for (int j = 0; j < 8; ++j) v[j] = 0;
                }
                obsF[ch] = v;
            }
            acc0 = (f32x4){breg, breg, breg, breg};
            acc1 = (f32x4){0.f, 0.f, 0.f, 0.f};
            acc0 = MFMA(obsF[0], wiF[0], acc0, 0, 0, 0);
            acc1 = MFMA(obsF[1], wiF[1], acc1, 0, 0, 0);
            acc0 = MFMA(obsF[2], wiF[2], acc0, 0, 0, 0);
            acc1 = MFMA(obsF[3], wiF[3], acc1, 0, 0, 0);
        }

        // wait until h_t is fully published
        if (t > 0) {
            const unsigned target = 4u * (unsigned)t;
            bool ready;
            do {
                unsigned v = target;
                if (l < NCU)
                    v = __hip_atomic_load(&gflags[l], __ATOMIC_RELAXED, __HIP_MEMORY_SCOPE_AGENT);
                ready = (__all(v >= target) != 0);
            } while (!ready);
            __builtin_amdgcn_fence(__ATOMIC_ACQUIRE, "agent");
        }

        // load full-h A-frags for step t: row = n, k = ch*32 + kg*8 + j
        const short* hsrc = hg + ((size_t)(((t & 1) * NGRP + gx) * 16 + n)) * H_ + kg * 8;
        bf16x8 hF[16];
#pragma unroll
        for (int ch = 0; ch < 16; ++ch)
            hF[ch] = *(const bf16x8*)(hsrc + ch * 32);

        if (!last) {
#pragma unroll
            for (int ch = 0; ch < 8; ++ch)  acc0 = MFMA(hF[ch], whF[ch], acc0, 0, 0, 0);
#pragma unroll
            for (int ch = 8; ch < 16; ++ch) acc1 = MFMA(hF[ch], whF[ch], acc1, 0, 0, 0);

            // gather i,f,g,o across lanes (gate id = bits 2:3 of n)
            float nh[4];
#pragma unroll
            for (int r = 0; r < 4; ++r) {
                float x  = acc0[r] + acc1[r];
                float fx = __shfl_xor(x, 4);
                float gx_ = __shfl_xor(x, 8);
                float ox = __shfl_xor(x, 12);
                float iv = sigm(x);
                float fv = sigm(fx);
                float gv = tanh_(gx_);
                float ov = sigm(ox);
                float nc = fv * cst[r] + iv * gv;
                cst[r] = nc;
                nh[r] = ov * tanh_(nc);
            }
            if (owner) {
                short* dst = hg + ((size_t)((((t + 1) & 1) * NGRP + gx) * 16)) * H_ + hcol;
#pragma unroll
                for (int r = 0; r < 4; ++r) {
                    dst[(size_t)(kg * 4 + r) * H_] = f2bf(nh[r]);
                    hlast[r] = nh[r];
                }
            }
            __builtin_amdgcn_fence(__ATOMIC_RELEASE, "agent");
            if (l == 0)
                __hip_atomic_fetch_add(&gflags[k], 1u, __ATOMIC_RELAXED, __HIP_MEMORY_SCOPE_AGENT);
        }

        // qs[t-1] = h_t @ Wv + bv, by CUs 0,1 only, after publish
        if (qcu && t > 0) {
            f32x4 qa = (f32x4){bvv, bvv, bvv, bvv};
#pragma unroll
            for (int ch = 0; ch < 16; ++ch) qa = MFMA(hF[ch], wvF[ch], qa, 0, 0, 0);
            if (qcol < A_) {
#pragma unroll
                for (int r = 0; r < 4; ++r) {
                    int brow = kg * 4 + r;
                    if (brow < GB)
                        out[(size_t)2 * B_ * H_ +
                            ((size_t)(gx * GB + brow) * T_ + (t - 1)) * A_ + qcol] = qa[r];
                }
            }
        }
    }

    // final c, h (fp32, from register state)
    if (owner) {
#pragma unroll
        for (int r = 0; r < 4; ++r) {
            int brow = gx * GB + kg * 4 + r;
            out[(size_t)brow * H_ + hcol] = cst[r];
            out[(size_t)B_ * H_ + (size_t)brow * H_ + hcol] = hlast[r];
        }
    }
}

extern "C" void kernel_launch(void* const* d_in, const int* in_sizes, int n_in,
                              void* d_out, int out_size, void* d_ws, size_t ws_size,
                              hipStream_t stream) {
    const float* obses  = (const float*)d_in[0];
    const float* init_c = (const float*)d_in[1];
    const float* init_h = (const float*)d_in[2];
    const float* Wi     = (const float*)d_in[3];
    const float* Wh     = (const float*)d_in[4];
    const float* b      = (const float*)d_in[5];
    const float* Wv     = (const float*)d_in[6];
    const float* bv     = (const float*)d_in[7];
    float* out = (float*)d_out;

    unsigned* flags = (unsigned*)d_ws;
    short*    hg    = (short*)((char*)d_ws + HG_OFF);

    hipLaunchKernelGGL(lstm_init, dim3(64), dim3(256), 0, stream, init_h, flags, hg);
    hipLaunchKernelGGL(lstm_main, dim3(256), dim3(256), 0, stream,
                       obses, init_c, Wi, Wh, b, Wv, bv, out, flags, hg);
}

// Round 2
// 22238.853 us; speedup vs baseline: 4.8930x; 4.8930x over previous
//
#include <hip/hip_runtime.h>
#include <stdint.h>
#include <stddef.h>

// LSTMQNetwork: B=64, T=4096, D=128, H=512, A=18
//
// Persistent-RNN, fence-free design:
//  - 128 recurrence blocks: 8 groups (bid&7 ~ XCD) x 16 CUs; CU owns 32
//    h-cols (2 MFMA col-tiles per wave). Wh/Wi stationary in VGPRs.
//  - h published per step into a t-indexed ring (R slots) via agent-scope
//    relaxed atomic dword stores (write-through to LIC); consumers read via
//    agent-scope relaxed atomic u64 loads. No acquire/release fences.
//  - per-CU monotonic flags (one per 64B line); inline-asm s_waitcnt vmcnt(0)
//    + __syncthreads orders stores before the flag add.
//  - 8 worker blocks (one per group, 4 waves interleaving steps mod 4)
//    compute qs = h @ Wv behind the producers; back-pressure via qdone
//    counters checked every R/4 steps.

#define B_   64
#define T_   4096
#define D_   128
#define H_   512
#define G4_  2048
#define A_   18
#define QOFF (2 * B_ * H_)

typedef float f32x4  __attribute__((ext_vector_type(4)));
typedef short bf16x8 __attribute__((ext_vector_type(8)));
#define MFMA __builtin_amdgcn_mfma_f32_16x16x32_bf16

// control region (dword indices into ws)
#define FLG_IDX(g,k) (((g)*16 + (k)) * 16)          // [0, 2048)
#define QD_IDX(g,w)  (2048 + ((g)*4 + (w)) * 16)    // [2048, 2560)
#define CTL_DWORDS   4096                            // zeroed region (16 KiB)
#define HS_OFF       65536                           // byte offset of h ring

__device__ __forceinline__ short f2bf(float x) {
    union { float f; uint32_t u; } v; v.f = x;
    uint32_t r = (v.u + 0x7fffu + ((v.u >> 16) & 1u)) >> 16;  // RNE
    return (short)(uint16_t)r;
}
__device__ __forceinline__ float sigm(float x) {
    return __builtin_amdgcn_rcpf(1.0f + __builtin_amdgcn_exp2f(-1.4426950408889634f * x));
}
__device__ __forceinline__ float tanh_(float x) {
    return 2.0f * __builtin_amdgcn_rcpf(1.0f + __builtin_amdgcn_exp2f(-2.8853900817779268f * x)) - 1.0f;
}

__global__ void lstm_init(const float* __restrict__ init_h,
                          unsigned* __restrict__ ctl,
                          short* __restrict__ hs, int R) {
    int idx = blockIdx.x * blockDim.x + threadIdx.x;
    int nt  = gridDim.x * blockDim.x;
    for (int i = idx; i < CTL_DWORDS; i += nt) ctl[i] = 0u;
    for (int e = idx; e < B_ * H_; e += nt) {
        int row = e >> 9, col = e & 511;
        int g = row >> 3, r8 = row & 7;
        hs[(size_t)g * R * 4096 + (size_t)r8 * 512 + col] = f2bf(init_h[e]);
    }
}

__global__ void __launch_bounds__(256, 1) lstm_main(
    const float* __restrict__ obses, const float* __restrict__ init_c,
    const float* __restrict__ Wi,    const float* __restrict__ Wh,
    const float* __restrict__ bvec,  const float* __restrict__ Wv,
    const float* __restrict__ bv,    float* __restrict__ out,
    unsigned* ctl, short* hs, int R)
{
    const int bid = blockIdx.x;
    const int w   = threadIdx.x >> 6;
    const int l   = threadIdx.x & 63;
    const int n   = l & 15;
    const int kg  = l >> 4;
    const int Rm  = R - 1;

    if (bid < 128) {
        // ---------------- recurrence producer ----------------
        const int g = bid & 7;
        const int k = bid >> 3;            // 0..15
        short*    hsg = hs + (size_t)g * R * 4096;
        unsigned* flg = ctl + FLG_IDX(g, 0);

        const int colb = k * 32 + w * 8 + (n & 3);
        const int gate = n >> 2;

        bf16x8 whF[2][16]; bf16x8 wiF[2][4]; float breg[2];
#pragma unroll
        for (int c = 0; c < 2; ++c) {
            const int gcol = gate * 512 + colb + c * 4;
#pragma unroll
            for (int ch = 0; ch < 16; ++ch) {
                bf16x8 v;
#pragma unroll
                for (int j = 0; j < 8; ++j)
                    v[j] = f2bf(Wh[(size_t)(ch * 32 + kg * 8 + j) * G4_ + gcol]);
                whF[c][ch] = v;
            }
#pragma unroll
            for (int ch = 0; ch < 4; ++ch) {
                bf16x8 v;
#pragma unroll
                for (int j = 0; j < 8; ++j)
                    v[j] = f2bf(Wi[(size_t)(ch * 32 + kg * 8 + j) * G4_ + gcol]);
                wiF[c][ch] = v;
            }
            breg[c] = bvec[gcol];
        }

        const bool owner = (kg < 2) && (n < 4);
        float cst[2][4], hlast[2][4];
#pragma unroll
        for (int c = 0; c < 2; ++c)
#pragma unroll
            for (int r = 0; r < 4; ++r) {
                cst[c][r] = owner ? init_c[(size_t)(g * 8 + kg * 4 + r) * H_ + colb + c * 4] : 0.f;
                hlast[c][r] = 0.f;
            }

        const int CHK  = (R >= 4) ? (R >> 2) : 1;
        const int CHKm = CHK - 1;

        for (int t = 0; t < T_; ++t) {
            // ---- back-pressure vs qs workers (rare) ----
            if ((t & CHKm) == 0) {
                const int need = t + CHK + 1 - R;
                if (need > 0) {
                    bool ok;
                    do {
                        int p = 0x7fffffff;
                        if (l < 4)
                            p = 1 + l + 4 * (int)__hip_atomic_load(ctl + QD_IDX(g, l),
                                    __ATOMIC_RELAXED, __HIP_MEMORY_SCOPE_AGENT);
                        ok = (__all(p >= need) != 0);
                    } while (!ok);
                }
            }

            // ---- x-projection (independent of h_t; overlaps the wait) ----
            f32x4 acc0 = {breg[0], breg[0], breg[0], breg[0]};
            f32x4 acc1 = {breg[1], breg[1], breg[1], breg[1]};
            {
                bf16x8 obsF[4];
#pragma unroll
                for (int ch = 0; ch < 4; ++ch) {
                    bf16x8 v;
                    if (n < 8) {
                        const float* src = obses + ((size_t)(g * 8 + n) * T_ + t) * D_ + ch * 32 + kg * 8;
                        f32x4 a  = *(const f32x4*)src;
                        f32x4 b2 = *(const f32x4*)(src + 4);
#pragma unroll
                        for (int j = 0; j < 4; ++j) { v[j] = f2bf(a[j]); v[4 + j] = f2bf(b2[j]); }
                    } else {
#pragma unroll
                        for (int j = 0; j < 8; ++j) v[j] = 0;
                    }
                    obsF[ch] = v;
                }
#pragma unroll
                for (int ch = 0; ch < 4; ++ch) {
                    acc0 = MFMA(obsF[ch], wiF[0][ch], acc0, 0, 0, 0);
                    acc1 = MFMA(obsF[ch], wiF[1][ch], acc1, 0, 0, 0);
                }
            }

            // ---- wait for h_t (all 16 CUs of group published) ----
            if (t > 0) {
                const unsigned tgt = (unsigned)t;
                bool ready;
                do {
                    unsigned v = tgt;
                    if (l < 16)
                        v = __hip_atomic_load(flg + l * 16, __ATOMIC_RELAXED, __HIP_MEMORY_SCOPE_AGENT);
                    ready = (__all(v >= tgt) != 0);
                } while (!ready);
                asm volatile("" ::: "memory");
            }

            // ---- load h_t fragments (agent-scope, bypass stale caches) ----
            bf16x8 hF[16];
            const int sl = t & Rm;
            if (n < 8) {
                const unsigned long long* hp =
                    (const unsigned long long*)(hsg + (size_t)sl * 4096 + (size_t)n * 512);
#pragma unroll
                for (int ch = 0; ch < 16; ++ch) {
                    union { unsigned long long q[2]; bf16x8 v; } u;
                    u.q[0] = __hip_atomic_load(hp + ch * 8 + kg * 2,     __ATOMIC_RELAXED, __HIP_MEMORY_SCOPE_AGENT);
                    u.q[1] = __hip_atomic_load(hp + ch * 8 + kg * 2 + 1, __ATOMIC_RELAXED, __HIP_MEMORY_SCOPE_AGENT);
                    hF[ch] = u.v;
                }
            } else {
#pragma unroll
                for (int ch = 0; ch < 16; ++ch) {
                    bf16x8 z;
#pragma unroll
                    for (int j = 0; j < 8; ++j) z[j] = 0;
                    hF[ch] = z;
                }
            }

#pragma unroll
            for (int ch = 0; ch < 16; ++ch) {
                acc0 = MFMA(hF[ch], whF[0][ch], acc0, 0, 0, 0);
                acc1 = MFMA(hF[ch], whF[1][ch], acc1, 0, 0, 0);
            }

            // ---- gates, state update, publish h_{t+1} ----
            const int slw = (t + 1) & Rm;
#pragma unroll
            for (int c = 0; c < 2; ++c) {
                const f32x4 acc = c ? acc1 : acc0;
#pragma unroll
                for (int r = 0; r < 4; ++r) {
                    float x  = acc[r];
                    float fx = __shfl_xor(x, 4);
                    float gg = __shfl_xor(x, 8);
                    float ox = __shfl_xor(x, 12);
                    float iv = sigm(x), fv = sigm(fx), gv = tanh_(gg), ov = sigm(ox);
                    float nc = fv * cst[c][r] + iv * gv;
                    float nh = ov * tanh_(nc);
                    float oth = __shfl_xor(nh, 1);
                    if (owner) {
                        cst[c][r] = nc; hlast[c][r] = nh;
                        if ((n & 1) == 0) {
                            unsigned dw = (unsigned)(unsigned short)f2bf(nh) |
                                          ((unsigned)(unsigned short)f2bf(oth) << 16);
                            unsigned* dst = (unsigned*)(hsg + (size_t)slw * 4096 +
                                                        (size_t)(kg * 4 + r) * 512 + colb + c * 4);
                            __hip_atomic_store(dst, dw, __ATOMIC_RELAXED, __HIP_MEMORY_SCOPE_AGENT);
                        }
                    }
                }
            }
            asm volatile("s_waitcnt vmcnt(0)" ::: "memory");
            __syncthreads();
            if (threadIdx.x == 0)
                __hip_atomic_fetch_add(flg + k * 16, 1u, __ATOMIC_RELAXED, __HIP_MEMORY_SCOPE_AGENT);
        }

        // ---- final c, h (fp32 from registers) ----
        if (owner) {
#pragma unroll
            for (int c = 0; c < 2; ++c)
#pragma unroll
                for (int r = 0; r < 4; ++r) {
                    const int brow = g * 8 + kg * 4 + r;
                    out[(size_t)brow * H_ + colb + c * 4] = cst[c][r];
                    out[(size_t)B_ * H_ + (size_t)brow * H_ + colb + c * 4] = hlast[c][r];
                }
        }
    } else {
        // ---------------- qs worker (1 CU per group) ----------------
        const int g = bid - 128;
        short*    hsg = hs + (size_t)g * R * 4096;
        unsigned* flg = ctl + FLG_IDX(g, 0);

        bf16x8 wvF[2][16]; float bvv[2];
#pragma unroll
        for (int c = 0; c < 2; ++c) {
            const int a  = c * 16 + n;
            const bool va = (a < A_);
#pragma unroll
            for (int ch = 0; ch < 16; ++ch) {
                bf16x8 v;
#pragma unroll
                for (int j = 0; j < 8; ++j)
                    v[j] = va ? f2bf(Wv[(size_t)(ch * 32 + kg * 8 + j) * A_ + a]) : (short)0;
                wvF[c][ch] = v;
            }
            bvv[c] = va ? bv[a] : 0.f;
        }

        unsigned cnt = 0;
        for (int s = 1 + w; s <= T_; s += 4) {
            const unsigned tgt = (unsigned)s;
            bool ready;
            do {
                unsigned v = tgt;
                if (l < 16)
                    v = __hip_atomic_load(flg + l * 16, __ATOMIC_RELAXED, __HIP_MEMORY_SCOPE_AGENT);
                ready = (__all(v >= tgt) != 0);
                if (!ready) __builtin_amdgcn_s_sleep(2);
            } while (!ready);
            asm volatile("" ::: "memory");

            bf16x8 hF[16];
            const int sl = s & Rm;
            if (n < 8) {
                const unsigned long long* hp =
                    (const unsigned long long*)(hsg + (size_t)sl * 4096 + (size_t)n * 512);
#pragma unroll
                for (int ch = 0; ch < 16; ++ch) {
                    union { unsigned long long q[2]; bf16x8 v; } u;
                    u.q[0] = __hip_atomic_load(hp + ch * 8 + kg * 2,     __ATOMIC_RELAXED, __HIP_MEMORY_SCOPE_AGENT);
                    u.q[1] = __hip_atomic_load(hp + ch * 8 + kg * 2 + 1, __ATOMIC_RELAXED, __HIP_MEMORY_SCOPE_AGENT);
                    hF[ch] = u.v;
                }
            } else {
#pragma unroll
                for (int ch = 0; ch < 16; ++ch) {
                    bf16x8 z;
#pragma unroll
                    for (int j = 0; j < 8; ++j) z[j] = 0;
                    hF[ch] = z;
                }
            }

            f32x4 q0 = {bvv[0], bvv[0], bvv[0], bvv[0]};
            f32x4 q1 = {bvv[1], bvv[1], bvv[1], bvv[1]};
#pragma unroll
            for (int ch = 0; ch < 16; ++ch) {
                q0 = MFMA(hF[ch], wvF[0][ch], q0, 0, 0, 0);
                q1 = MFMA(hF[ch], wvF[1][ch], q1, 0, 0, 0);
            }

            const int tau = s - 1;
#pragma unroll
            for (int c = 0; c < 2; ++c) {
                const int a = c * 16 + n;
                if (kg < 2 && a < A_) {
                    const f32x4 q = c ? q1 : q0;
#pragma unroll
                    for (int r = 0; r < 4; ++r)
                        out[QOFF + ((size_t)(g * 8 + kg * 4 + r) * T_ + tau) * A_ + a] = q[r];
                }
            }
            ++cnt;
            asm volatile("" ::: "memory");
            if (l == 0)
                __hip_atomic_store(ctl + QD_IDX(g, w), cnt, __ATOMIC_RELAXED, __HIP_MEMORY_SCOPE_AGENT);
        }
    }
}

extern "C" void kernel_launch(void* const* d_in, const int* in_sizes, int n_in,
                              void* d_out, int out_size, void* d_ws, size_t ws_size,
                              hipStream_t stream) {
    const float* obses  = (const float*)d_in[0];
    const float* init_c = (const float*)d_in[1];
    const float* init_h = (const float*)d_in[2];
    const float* Wi     = (const float*)d_in[3];
    const float* Wh     = (const float*)d_in[4];
    const float* b      = (const float*)d_in[5];
    const float* Wv     = (const float*)d_in[6];
    const float* bv     = (const float*)d_in[7];
    float* out = (float*)d_out;

    unsigned* ctl = (unsigned*)d_ws;
    short*    hs  = (short*)((char*)d_ws + HS_OFF);

    // ring slots: R * 64KiB of h storage + 64KiB control, capped at 512
    int R = 512;
    while (R > 2 && (size_t)HS_OFF + (size_t)R * 65536 > ws_size) R >>= 1;

    hipLaunchKernelGGL(lstm_init, dim3(64), dim3(256), 0, stream, init_h, ctl, hs, R);
    hipLaunchKernelGGL(lstm_main, dim3(136), dim3(256), 0, stream,
                       obses, init_c, Wi, Wh, b, Wv, bv, out, ctl, hs, R);
}